// Round 9
// baseline (64.557 us; speedup 1.0000x reference)
//
#include <hip/hip_runtime.h>

// Problem constants: B=8, S=2048, D=512, G=2, V=320, CV=128
#define M_ROWS 16384   // B*S
#define K_DIM  512
#define N_COLS 640     // G*V
#define V_CODES 320
#define CV_DIM 128

typedef _Float16 half8 __attribute__((ext_vector_type(8)));
typedef _Float16 half4v __attribute__((ext_vector_type(4)));
typedef float floatx4 __attribute__((ext_vector_type(4)));

// ---------------------------------------------------------------------------
// Kernel 0: prepW — LDS-tiled transpose W (512,640) f32 -> Wt (640,512) f16;
// block 320 zeroes the global marginal.
// ---------------------------------------------------------------------------
__global__ __launch_bounds__(256)
void prepW(const float* __restrict__ W, _Float16* __restrict__ Wt,
           float* __restrict__ marginal) {
    __shared__ float tile[32][33];
    const int b = blockIdx.x, t = threadIdx.x;
    if (b == 320) {
        for (int i = t; i < 640; i += 256) marginal[i] = 0.f;
        return;
    }
    const int n0 = (b % 20) * 32, k0 = (b / 20) * 32;
    {
        const int kk = t >> 3, nn4 = (t & 7) << 2;
        const float4 w = *(const float4*)(W + (size_t)(k0 + kk) * 640 + n0 + nn4);
        tile[kk][nn4 + 0] = w.x; tile[kk][nn4 + 1] = w.y;
        tile[kk][nn4 + 2] = w.z; tile[kk][nn4 + 3] = w.w;
    }
    __syncthreads();
    {
        const int nn = t >> 3, kk4 = (t & 7) << 2;
        half4v h = {(_Float16)tile[kk4 + 0][nn], (_Float16)tile[kk4 + 1][nn],
                    (_Float16)tile[kk4 + 2][nn], (_Float16)tile[kk4 + 3][nn]};
        *(half4v*)(Wt + (size_t)(n0 + nn) * 512 + k0 + kk4) = h;
    }
}

// ---------------------------------------------------------------------------
// Fused kernel (barrier-free K-loop):
// grid (256 bm, 2 g), 256 threads = 4 waves.
// A-tile (64x512) staged ONCE to LDS (f32->f16, XOR-swizzle chunk^(row&7)).
// Wave w owns ALL 64 token-rows x cols [w*80, w*80+80): acc[4 mt][5 nt].
// B fragments are per-wave-unique -> loaded straight from global (L2-resident
// Wt) into registers with explicit next-step prefetch; no LDS, no barriers,
// no vmcnt(0) drain in the K-loop.
// Epilogue: per-quarter-wave row partials (argmax / expsum over 80 cols) ->
// LDS -> cross-wave combine (t<64) -> marginal atomics + cv gather/out.
// ---------------------------------------------------------------------------
__global__ __launch_bounds__(256, 2)
void fused(const float* __restrict__ A, const _Float16* __restrict__ Bt,
           const float* __restrict__ bias, const float* __restrict__ gum,
           const float* __restrict__ cv, float* __restrict__ out,
           float* __restrict__ marginal) {
    __shared__ _Float16 As[64 * 512];   // 64 KB, swizzled
    __shared__ float wbest[4][64];
    __shared__ int   wbidx[4][64];
    __shared__ float wsum[4][64];
    __shared__ int   fbidx[64];
    __shared__ float finv[64];

    const int t = threadIdx.x;
    const int wave = t >> 6, lane = t & 63;
    const int bm = blockIdx.x, g = blockIdx.y;
    const int c = lane & 15, kq = lane >> 4;

    // ---- prologue: stage A tile once (f32 -> f16, swizzled) ----
    {
        const int am = t >> 2;              // row 0..63
        const int kb = (t & 3) * 128;       // k base (4 threads/row)
        const float* Ap = A + (size_t)(bm * 64 + am) * 512 + kb;
#pragma unroll
        for (int i = 0; i < 16; ++i) {
            const float4 v0 = *(const float4*)(Ap + i * 8);
            const float4 v1 = *(const float4*)(Ap + i * 8 + 4);
            const half8 h = {(_Float16)v0.x, (_Float16)v0.y, (_Float16)v0.z,
                             (_Float16)v0.w, (_Float16)v1.x, (_Float16)v1.y,
                             (_Float16)v1.z, (_Float16)v1.w};
            const int chunk = ((kb >> 3) + i) ^ (am & 7);
            *(half8*)((char*)As + am * 1024 + chunk * 16) = h;
        }
    }
    __syncthreads();

    floatx4 acc[4][5];
#pragma unroll
    for (int mt = 0; mt < 4; ++mt)
#pragma unroll
        for (int nt = 0; nt < 5; ++nt) acc[mt][nt] = (floatx4){0.f, 0.f, 0.f, 0.f};

    const _Float16* Bg = Bt + (size_t)g * V_CODES * K_DIM
                            + (size_t)(wave * 80 + c) * K_DIM + kq * 8;

    // ---- barrier-free K loop: B global->reg prefetch, A ds_read, MFMA ----
    half8 bcur[5], bnxt[5], af[4];
#pragma unroll
    for (int nt = 0; nt < 5; ++nt)
        bcur[nt] = *(const half8*)(Bg + (size_t)nt * 16 * K_DIM);

#pragma unroll 2
    for (int kt = 0; kt < 16; ++kt) {
        if (kt < 15) {
#pragma unroll
            for (int nt = 0; nt < 5; ++nt)
                bnxt[nt] = *(const half8*)(Bg + (size_t)nt * 16 * K_DIM
                                           + (kt + 1) * 32);
        }
#pragma unroll
        for (int mt = 0; mt < 4; ++mt) {
            const int ra = mt * 16 + c;
            const int chunk = (kt * 4 + kq) ^ (ra & 7);
            af[mt] = *(const half8*)((const char*)As + ra * 1024 + chunk * 16);
        }
#pragma unroll
        for (int mt = 0; mt < 4; ++mt)
#pragma unroll
            for (int nt = 0; nt < 5; ++nt)
                acc[mt][nt] = __builtin_amdgcn_mfma_f32_16x16x32_f16(
                    af[mt], bcur[nt], acc[mt][nt], 0, 0, 0);
#pragma unroll
        for (int nt = 0; nt < 5; ++nt) bcur[nt] = bnxt[nt];
    }

    // ---- epilogue ----
    // bias add (in place)
    float bcol[5];
#pragma unroll
    for (int nt = 0; nt < 5; ++nt)
        bcol[nt] = bias[g * V_CODES + wave * 80 + nt * 16 + c];
#pragma unroll
    for (int mt = 0; mt < 4; ++mt)
#pragma unroll
        for (int nt = 0; nt < 5; ++nt)
#pragma unroll
            for (int rg = 0; rg < 4; ++rg) acc[mt][nt][rg] += bcol[nt];

    __syncthreads();   // A-LDS no longer needed; scratch phase begins

    // per-(mt,rg): quarter-wave argmax(L+gumbel) + exp-in-place + sum partials
#pragma unroll
    for (int mt = 0; mt < 4; ++mt) {
#pragma unroll
        for (int rg = 0; rg < 4; ++rg) {
            const int r = mt * 16 + kq * 4 + rg;    // block-local token row
            const float* gr = gum + ((size_t)(bm * 64 + r) * 2 + g) * V_CODES
                              + wave * 80 + c;
            float best = -1e30f; int bidx = 0;
#pragma unroll
            for (int nt = 0; nt < 5; ++nt) {
                const float nz = acc[mt][nt][rg] + gr[nt * 16];
                const int v = wave * 80 + nt * 16 + c;
                if (nz > best) { best = nz; bidx = v; }
            }
#pragma unroll
            for (int mask = 1; mask <= 8; mask <<= 1) {
                const float ob = __shfl_xor(best, mask);
                const int   oi = __shfl_xor(bidx, mask);
                if (ob > best || (ob == best && oi < bidx)) { best = ob; bidx = oi; }
            }
            float s = 0.f;
#pragma unroll
            for (int nt = 0; nt < 5; ++nt) {
                const float e = __expf(acc[mt][nt][rg]);
                acc[mt][nt][rg] = e;                 // keep exp for marginal
                s += e;
            }
#pragma unroll
            for (int mask = 1; mask <= 8; mask <<= 1) s += __shfl_xor(s, mask);
            if (c == 0) {
                wbest[wave][r] = best;
                wbidx[wave][r] = bidx;
                wsum[wave][r]  = s;
            }
        }
    }
    __syncthreads();

    // cross-wave combine: final argmax + 1/sum per row
    if (t < 64) {
        float best = wbest[0][t]; int bi = wbidx[0][t];
        float s = wsum[0][t];
#pragma unroll
        for (int w = 1; w < 4; ++w) {
            const float ob = wbest[w][t]; const int oi = wbidx[w][t];
            if (ob > best || (ob == best && oi < bi)) { best = ob; bi = oi; }
            s += wsum[w][t];
        }
        fbidx[t] = bi;
        finv[t] = 1.f / s;
    }
    __syncthreads();

    // marginal: mcon[nt] = sum over this wave's rows of exp * inv
    float mcon[5];
#pragma unroll
    for (int nt = 0; nt < 5; ++nt) mcon[nt] = 0.f;
#pragma unroll
    for (int mt = 0; mt < 4; ++mt) {
#pragma unroll
        for (int rg = 0; rg < 4; ++rg) {
            const float iv = finv[mt * 16 + kq * 4 + rg];
#pragma unroll
            for (int nt = 0; nt < 5; ++nt) mcon[nt] += acc[mt][nt][rg] * iv;
        }
    }
#pragma unroll
    for (int nt = 0; nt < 5; ++nt) {
        mcon[nt] += __shfl_xor(mcon[nt], 16);
        mcon[nt] += __shfl_xor(mcon[nt], 32);
    }
    if (lane < 16) {
#pragma unroll
        for (int nt = 0; nt < 5; ++nt)
            atomicAdd(marginal + g * V_CODES + wave * 80 + nt * 16 + c, mcon[nt]);
    }

    // out: wave writes rows [wave*16, wave*16+16), one-hot codevector gather
#pragma unroll
    for (int rr = 0; rr < 4; ++rr) {
        const int row = wave * 16 + kq * 4 + rr;
        const int bi = fbidx[row];
        const float4* cvp = (const float4*)(cv + ((size_t)g * V_CODES + bi) * CV_DIM)
                            + c * 2;
        const float4 v0 = cvp[0], v1 = cvp[1];
        float4* op = (float4*)(out + (size_t)(bm * 64 + row) * 256 + g * CV_DIM)
                     + c * 2;
        op[0] = v0; op[1] = v1;
    }
}

// ---------------------------------------------------------------------------
// Kernel 2: finalize perplexity from the global marginal (640 floats).
// ---------------------------------------------------------------------------
__global__ __launch_bounds__(640)
void finalize(const float* __restrict__ marginal, float* __restrict__ perp_out) {
    __shared__ float terms[640];
    __shared__ float gsum[2];
    const int t = threadIdx.x;

    const float m = marginal[t] * (1.0f / (float)M_ROWS);
    terms[t] = -m * __logf(m + 1e-7f);
    __syncthreads();

    if (t < 128) {
        const int g = t >> 6, lane = t & 63;
        float e = 0.f;
#pragma unroll
        for (int j = 0; j < 5; ++j) e += terms[g * V_CODES + lane + 64 * j];
#pragma unroll
        for (int off = 32; off; off >>= 1) e += __shfl_down(e, off);
        if (lane == 0) gsum[g] = e;
    }
    __syncthreads();
    if (t == 0) perp_out[0] = __expf(gsum[0]) + __expf(gsum[1]);
}

// ---------------------------------------------------------------------------
extern "C" void kernel_launch(void* const* d_in, const int* in_sizes, int n_in,
                              void* d_out, int out_size, void* d_ws, size_t ws_size,
                              hipStream_t stream) {
    (void)in_sizes; (void)n_in; (void)out_size; (void)ws_size;
    const float* hs = (const float*)d_in[0];   // (8,2048,512) f32
    const float* W  = (const float*)d_in[1];   // (512,640)    f32
    const float* bi = (const float*)d_in[2];   // (640,)       f32
    const float* cv = (const float*)d_in[3];   // (1,640,128)  f32
    const float* gu = (const float*)d_in[4];   // (32768,320)  f32
    float* out = (float*)d_out;                // 16384*256 + 1

    // ws: Wt f16 (640 KB) + marginal (640 f32)
    _Float16* Wt       = (_Float16*)d_ws;
    float*    marginal = (float*)(Wt + (size_t)N_COLS * K_DIM);

    prepW<<<321, 256, 0, stream>>>(W, Wt, marginal);
    fused<<<dim3(256, 2), 256, 0, stream>>>(hs, Wt, bi, gu, cv, out, marginal);
    finalize<<<1, 640, 0, stream>>>(marginal, out + (size_t)M_ROWS * 256);
}

// Round 10
// 57.449 us; speedup vs baseline: 1.1237x; 1.1237x over previous
//
#include <hip/hip_runtime.h>

// Problem constants: B=8, S=2048, D=512, G=2, V=320, CV=128
#define M_ROWS 16384   // B*S
#define K_DIM  512
#define N_COLS 640     // G*V
#define V_CODES 320
#define CV_DIM 128
#define NREP 8         // marginal replicas (atomic decontention)

typedef _Float16 half8 __attribute__((ext_vector_type(8)));
typedef _Float16 half4v __attribute__((ext_vector_type(4)));
typedef float floatx4 __attribute__((ext_vector_type(4)));

__device__ inline void gll16(const void* g, void* l) {
    __builtin_amdgcn_global_load_lds(
        (const __attribute__((address_space(1))) void*)g,
        (__attribute__((address_space(3))) void*)l, 16, 0, 0);
}

// ---------------------------------------------------------------------------
// Kernel 0: prepW — LDS-tiled transpose W (512,640) f32 -> Wt (640,512) f16;
// block 320 zeroes the replicated marginal.
// ---------------------------------------------------------------------------
__global__ __launch_bounds__(256)
void prepW(const float* __restrict__ W, _Float16* __restrict__ Wt,
           float* __restrict__ marg8) {
    __shared__ float tile[32][33];
    const int b = blockIdx.x, t = threadIdx.x;
    if (b == 320) {
        for (int i = t; i < NREP * 640; i += 256) marg8[i] = 0.f;
        return;
    }
    const int n0 = (b % 20) * 32, k0 = (b / 20) * 32;
    {
        const int kk = t >> 3, nn4 = (t & 7) << 2;
        const float4 w = *(const float4*)(W + (size_t)(k0 + kk) * 640 + n0 + nn4);
        tile[kk][nn4 + 0] = w.x; tile[kk][nn4 + 1] = w.y;
        tile[kk][nn4 + 2] = w.z; tile[kk][nn4 + 3] = w.w;
    }
    __syncthreads();
    {
        const int nn = t >> 3, kk4 = (t & 7) << 2;
        half4v h = {(_Float16)tile[kk4 + 0][nn], (_Float16)tile[kk4 + 1][nn],
                    (_Float16)tile[kk4 + 2][nn], (_Float16)tile[kk4 + 3][nn]};
        *(half4v*)(Wt + (size_t)(n0 + nn) * 512 + k0 + kk4) = h;
    }
}

// ---------------------------------------------------------------------------
// Fused kernel: BM=32, grid (512 bm, 2 g) = 1024 blocks -> 3 resident
// blocks/CU (LDS ~47 KB), 4 waves. Wave (mi = w>>1, nh = w&1) computes
// 16 rows x 160 cols: acc[10]. K-loop: round-8-proven dbuf gll16 staging
// (BK=32), one barrier per step. Epilogue: per-wave row partials over 160
// cols -> LDS cross-half combine -> marginal (replicated atomics) + cv/out.
// ---------------------------------------------------------------------------
__global__ __launch_bounds__(256, 3)
void fused(const float* __restrict__ A, const _Float16* __restrict__ Bt,
           const float* __restrict__ bias, const float* __restrict__ gum,
           const float* __restrict__ cv, float* __restrict__ out,
           float* __restrict__ marg8) {
    __shared__ _Float16 Bs[2][320 * 32];   // 2 x 20 KB
    __shared__ _Float16 As[2][32 * 32];    // 2 x 2 KB
    __shared__ float smarg[320];
    __shared__ float wbest[2][32];
    __shared__ float wsum[2][32];
    __shared__ int   wbidx[2][32];
    __shared__ int   fbidx[32];
    __shared__ float finv[32];

    const int t = threadIdx.x;
    const int wave = t >> 6, lane = t & 63;
    const int bm = blockIdx.x, g = blockIdx.y;
    const int mi = wave >> 1, nh = wave & 1;
    const int c = lane & 15, kq = lane >> 4;

    for (int i = t; i < 320; i += 256) smarg[i] = 0.f;

    floatx4 acc[10];
#pragma unroll
    for (int nt = 0; nt < 10; ++nt) acc[nt] = (floatx4){0.f, 0.f, 0.f, 0.f};

    // A staging map: thread -> (row arow, float4-group ak4); swizzled 8B write
    const int arow = t >> 3, ak4 = t & 7;
    const int a_wr = arow * 64 + ((((ak4 >> 1) ^ (arow & 3))) << 4) + (ak4 & 1) * 8;
    const float* Aptr = A + (size_t)(bm * 32 + arow) * 512 + ak4 * 4;

    const _Float16* Bg = Bt + (size_t)g * V_CODES * K_DIM;

    auto STAGE = [&](int buf, int k0) {
        const float4 av = *(const float4*)(Aptr + k0);
#pragma unroll
        for (int s = 0; s < 5; ++s) {
            const int q = t + 256 * s;               // 0..1279
            const int n = q >> 2, j = q & 3;         // row 0..319, chunk 0..3
            gll16(Bg + (size_t)n * 512 + k0 + ((j ^ (n & 3)) << 3),
                  (char*)(&Bs[buf][0]) + q * 16);
        }
        const half4v h = {(_Float16)av.x, (_Float16)av.y,
                          (_Float16)av.z, (_Float16)av.w};
        *(half4v*)((char*)(&As[buf][0]) + a_wr) = h;
    };

    STAGE(0, 0);
    __syncthreads();

    for (int kt = 0; kt < 16; ++kt) {
        const int cur = kt & 1;
        if (kt < 15) STAGE(cur ^ 1, (kt + 1) * 32);
        const int ra = mi * 16 + c;
        const half8 af = *(const half8*)((const char*)(&As[cur][0]) +
                          ra * 64 + ((kq ^ (ra & 3)) << 4));
#pragma unroll
        for (int nt = 0; nt < 10; ++nt) {
            const int rb = nh * 160 + nt * 16 + c;
            const half8 bf = *(const half8*)((const char*)(&Bs[cur][0]) +
                              rb * 64 + ((kq ^ (rb & 3)) << 4));
            acc[nt] = __builtin_amdgcn_mfma_f32_16x16x32_f16(af, bf, acc[nt], 0, 0, 0);
        }
        __syncthreads();
    }

    // ---- epilogue ----
    float bcol[10];
#pragma unroll
    for (int nt = 0; nt < 10; ++nt)
        bcol[nt] = bias[g * V_CODES + nh * 160 + nt * 16 + c];
#pragma unroll
    for (int nt = 0; nt < 10; ++nt)
#pragma unroll
        for (int rg = 0; rg < 4; ++rg) acc[nt][rg] += bcol[nt];

    // per-row partials over this wave's 160 cols
#pragma unroll
    for (int rg = 0; rg < 4; ++rg) {
        const int rloc = mi * 16 + kq * 4 + rg;          // block-local row 0..31
        const float* gr = gum + ((size_t)(bm * 32 + rloc) * 2 + g) * V_CODES
                          + nh * 160 + c;
        float best = -1e30f; int bidx = 0;
#pragma unroll
        for (int nt = 0; nt < 10; ++nt) {
            const float nz = acc[nt][rg] + gr[nt * 16];
            const int v = nh * 160 + nt * 16 + c;        // group-local col
            if (nz > best) { best = nz; bidx = v; }
        }
#pragma unroll
        for (int mask = 1; mask <= 8; mask <<= 1) {
            const float ob = __shfl_xor(best, mask);
            const int   oi = __shfl_xor(bidx, mask);
            if (ob > best || (ob == best && oi < bidx)) { best = ob; bidx = oi; }
        }
        float s = 0.f;
#pragma unroll
        for (int nt = 0; nt < 10; ++nt) {
            const float e = __expf(acc[nt][rg]);
            acc[nt][rg] = e;                             // keep exp for marginal
            s += e;
        }
#pragma unroll
        for (int mask = 1; mask <= 8; mask <<= 1) s += __shfl_xor(s, mask);
        if (c == 0) {
            wbest[nh][rloc] = best;
            wbidx[nh][rloc] = bidx;
            wsum[nh][rloc]  = s;
        }
    }
    __syncthreads();

    // cross-half combine: final argmax + 1/sum per row
    if (t < 32) {
        float best = wbest[0][t]; int bi = wbidx[0][t];
        const float ob = wbest[1][t]; const int oi = wbidx[1][t];
        if (ob > best || (ob == best && oi < bi)) { best = ob; bi = oi; }
        fbidx[t] = bi;
        finv[t] = 1.f / (wsum[0][t] + wsum[1][t]);
    }
    __syncthreads();

    // marginal: sum exp*inv over this wave's 16 rows, its 160 cols
    float mcon[10];
#pragma unroll
    for (int nt = 0; nt < 10; ++nt) mcon[nt] = 0.f;
#pragma unroll
    for (int rg = 0; rg < 4; ++rg) {
        const float iv = finv[mi * 16 + kq * 4 + rg];
#pragma unroll
        for (int nt = 0; nt < 10; ++nt) mcon[nt] += acc[nt][rg] * iv;
    }
#pragma unroll
    for (int nt = 0; nt < 10; ++nt) {
        mcon[nt] += __shfl_xor(mcon[nt], 16);
        mcon[nt] += __shfl_xor(mcon[nt], 32);
    }
    if (lane < 16) {
#pragma unroll
        for (int nt = 0; nt < 10; ++nt)
            atomicAdd(&smarg[nh * 160 + nt * 16 + c], mcon[nt]);
    }
    __syncthreads();
    for (int i = t; i < 320; i += 256)
        atomicAdd(marg8 + (size_t)(bm & (NREP - 1)) * 640 + g * V_CODES + i,
                  smarg[i]);

    // out: 32 rows x 512B; each wave writes 8 rows, 8 lanes/row x 64B/lane
    {
        const int rowl = wave * 8 + (lane >> 3);
        const int p = lane & 7;
        const int bi = fbidx[rowl];
        const float4* cvp = (const float4*)(cv + ((size_t)g * V_CODES + bi) * CV_DIM)
                            + p * 4;
        const float4 v0 = cvp[0], v1 = cvp[1], v2 = cvp[2], v3 = cvp[3];
        float4* op = (float4*)(out + (size_t)(bm * 32 + rowl) * 256 + g * CV_DIM)
                     + p * 4;
        op[0] = v0; op[1] = v1; op[2] = v2; op[3] = v3;
    }
}

// ---------------------------------------------------------------------------
// Kernel 2: finalize perplexity from replicated marginal (8 x 640 floats).
// ---------------------------------------------------------------------------
__global__ __launch_bounds__(640)
void finalize(const float* __restrict__ marg8, float* __restrict__ perp_out) {
    __shared__ float terms[640];
    __shared__ float gsum[2];
    const int t = threadIdx.x;

    float s = 0.f;
#pragma unroll
    for (int k = 0; k < NREP; ++k) s += marg8[k * 640 + t];
    const float m = s * (1.0f / (float)M_ROWS);
    terms[t] = -m * __logf(m + 1e-7f);
    __syncthreads();

    if (t < 128) {
        const int g = t >> 6, lane = t & 63;
        float e = 0.f;
#pragma unroll
        for (int j = 0; j < 5; ++j) e += terms[g * V_CODES + lane + 64 * j];
#pragma unroll
        for (int off = 32; off; off >>= 1) e += __shfl_down(e, off);
        if (lane == 0) gsum[g] = e;
    }
    __syncthreads();
    if (t == 0) perp_out[0] = __expf(gsum[0]) + __expf(gsum[1]);
}

// ---------------------------------------------------------------------------
extern "C" void kernel_launch(void* const* d_in, const int* in_sizes, int n_in,
                              void* d_out, int out_size, void* d_ws, size_t ws_size,
                              hipStream_t stream) {
    (void)in_sizes; (void)n_in; (void)out_size; (void)ws_size;
    const float* hs = (const float*)d_in[0];   // (8,2048,512) f32
    const float* W  = (const float*)d_in[1];   // (512,640)    f32
    const float* bi = (const float*)d_in[2];   // (640,)       f32
    const float* cv = (const float*)d_in[3];   // (1,640,128)  f32
    const float* gu = (const float*)d_in[4];   // (32768,320)  f32
    float* out = (float*)d_out;                // 16384*256 + 1

    // ws: Wt f16 (640 KB) + marg8 (8*640 f32)
    _Float16* Wt    = (_Float16*)d_ws;
    float*    marg8 = (float*)(Wt + (size_t)N_COLS * K_DIM);

    prepW<<<321, 256, 0, stream>>>(W, Wt, marg8);
    fused<<<dim3(512, 2), 256, 0, stream>>>(hs, Wt, bi, gu, cv, out, marg8);
    finalize<<<1, 640, 0, stream>>>(marg8, out + (size_t)M_ROWS * 256);
}

// Round 11
// 50.723 us; speedup vs baseline: 1.2728x; 1.1326x over previous
//
#include <hip/hip_runtime.h>

// Problem constants: B=8, S=2048, D=512, G=2, V=320, CV=128
#define M_ROWS 16384   // B*S
#define K_DIM  512
#define N_COLS 640     // G*V
#define V_CODES 320
#define CV_DIM 128
#define LSTRIDE 330    // f16 logit-row stride in LDS (odd-ish: spreads banks)

typedef _Float16 half8 __attribute__((ext_vector_type(8)));
typedef _Float16 half4v __attribute__((ext_vector_type(4)));
typedef float floatx4 __attribute__((ext_vector_type(4)));

__device__ inline void gll16(const void* g, void* l) {
    __builtin_amdgcn_global_load_lds(
        (const __attribute__((address_space(1))) void*)g,
        (__attribute__((address_space(3))) void*)l, 16, 0, 0);
}

// ---------------------------------------------------------------------------
// Kernel 0: prepW — LDS-tiled transpose W (512,640) f32 -> Wt (640,512) f16;
// block 320 zeroes the global marginal.
// ---------------------------------------------------------------------------
__global__ __launch_bounds__(256)
void prepW(const float* __restrict__ W, _Float16* __restrict__ Wt,
           float* __restrict__ marginal) {
    __shared__ float tile[32][33];
    const int b = blockIdx.x, t = threadIdx.x;
    if (b == 320) {
        for (int i = t; i < 640; i += 256) marginal[i] = 0.f;
        return;
    }
    const int n0 = (b % 20) * 32, k0 = (b / 20) * 32;
    {
        const int kk = t >> 3, nn4 = (t & 7) << 2;
        const float4 w = *(const float4*)(W + (size_t)(k0 + kk) * 640 + n0 + nn4);
        tile[kk][nn4 + 0] = w.x; tile[kk][nn4 + 1] = w.y;
        tile[kk][nn4 + 2] = w.z; tile[kk][nn4 + 3] = w.w;
    }
    __syncthreads();
    {
        const int nn = t >> 3, kk4 = (t & 7) << 2;
        half4v h = {(_Float16)tile[kk4 + 0][nn], (_Float16)tile[kk4 + 1][nn],
                    (_Float16)tile[kk4 + 2][nn], (_Float16)tile[kk4 + 3][nn]};
        *(half4v*)(Wt + (size_t)(n0 + nn) * 512 + k0 + kk4) = h;
    }
}

// ---------------------------------------------------------------------------
// Fused kernel (round-8 geometry + phase-split epilogue):
// grid (256 bm, 2 g), 256 threads = 4 waves; wave mi owns 16 rows x all 320
// cols (acc[20]). K-loop: dbuf gll16 staging, BK=32, one barrier/step.
// Epilogue phase 1: acc+bias -> f16 logits in LDS (union over staging bufs;
// wave-local rows, no barrier) — FREES the 80 acc VGPRs.
// Phase 2: prefetch all 80 gumbel f32 into the freed registers (one latency
// wave instead of ~40 serial round-trips), argmax/softmax from LDS logits,
// cv gather + out, marginal via LDS + global atomics.
// ---------------------------------------------------------------------------
union SMemG {
    struct { _Float16 Bs[2][320 * 32]; _Float16 As[2][64 * 32]; } g;  // 48 KB
    _Float16 L[64 * LSTRIDE];                                         // 41.3 KB
};

__global__ __launch_bounds__(256, 3)
void fused(const float* __restrict__ A, const _Float16* __restrict__ Bt,
           const float* __restrict__ bias, const float* __restrict__ gum,
           const float* __restrict__ cv, float* __restrict__ out,
           float* __restrict__ marginal) {
    __shared__ SMemG sm;
    __shared__ float smarg[320];
    const int t = threadIdx.x;
    const int wave = t >> 6, lane = t & 63;
    const int bm = blockIdx.x, g = blockIdx.y;
    const int mi = wave;
    const int c = lane & 15, kq = lane >> 4;

    for (int i = t; i < 320; i += 256) smarg[i] = 0.f;

    floatx4 acc[20];
#pragma unroll
    for (int nt = 0; nt < 20; ++nt) acc[nt] = (floatx4){0.f, 0.f, 0.f, 0.f};

    // A staging map (round-8-proven): row am, 16B chunk ad, swizzle ^(am&3)
    const int am = t >> 2, ad = t & 3;
    const int a_wr = am * 64 + ((ad ^ (am & 3)) << 4);
    const float* Aptr = A + (size_t)(bm * 64 + am) * 512 + ad * 8;

    const _Float16* Bg = Bt + (size_t)g * V_CODES * K_DIM;

    auto STAGE = [&](int buf, int k0) {
        const float4 av0 = *(const float4*)(Aptr + k0);
        const float4 av1 = *(const float4*)(Aptr + k0 + 4);
#pragma unroll
        for (int s = 0; s < 5; ++s) {
            const int q = t + 256 * s;               // 0..1279
            const int n = q >> 2, j = q & 3;         // row 0..319, chunk 0..3
            gll16(Bg + (size_t)n * 512 + k0 + ((j ^ (n & 3)) << 3),
                  (char*)(&sm.g.Bs[buf][0]) + q * 16);
        }
        const half8 h = {(_Float16)av0.x, (_Float16)av0.y, (_Float16)av0.z,
                         (_Float16)av0.w, (_Float16)av1.x, (_Float16)av1.y,
                         (_Float16)av1.z, (_Float16)av1.w};
        *(half8*)((char*)(&sm.g.As[buf][0]) + a_wr) = h;
    };

    STAGE(0, 0);
    __syncthreads();

    for (int kt = 0; kt < 16; ++kt) {
        const int cur = kt & 1;
        if (kt < 15) STAGE(cur ^ 1, (kt + 1) * 32);
        const int ra = mi * 16 + c;
        const half8 af = *(const half8*)((const char*)(&sm.g.As[cur][0]) +
                          ra * 64 + ((kq ^ (ra & 3)) << 4));
#pragma unroll
        for (int nt = 0; nt < 20; ++nt) {
            const int rb = nt * 16 + c;
            const half8 bf = *(const half8*)((const char*)(&sm.g.Bs[cur][0]) +
                              rb * 64 + ((kq ^ (rb & 3)) << 4));
            acc[nt] = __builtin_amdgcn_mfma_f32_16x16x32_f16(af, bf, acc[nt], 0, 0, 0);
        }
        __syncthreads();   // final barrier also fences the union overwrite below
    }

    // ---- phase 1: acc + bias -> f16 logits in LDS; acc registers die here ----
    float bcol[20];
#pragma unroll
    for (int nt = 0; nt < 20; ++nt) bcol[nt] = bias[g * V_CODES + nt * 16 + c];
#pragma unroll
    for (int rg = 0; rg < 4; ++rg) {
        const int row = mi * 16 + kq * 4 + rg;       // per-lane row (kq varies)
#pragma unroll
        for (int nt = 0; nt < 20; ++nt)
            sm.L[row * LSTRIDE + nt * 16 + c] = (_Float16)(acc[nt][rg] + bcol[nt]);
    }
    // no barrier: each wave reads back only rows it wrote itself

    // ---- phase 2: gumbel prefetch into freed regs + row reductions ----
    float gv[4][20];
#pragma unroll
    for (int rg = 0; rg < 4; ++rg) {
        const int ntok = bm * 64 + mi * 16 + kq * 4 + rg;
        const float* gr = gum + ((size_t)ntok * 2 + g) * V_CODES + c;
#pragma unroll
        for (int nt = 0; nt < 20; ++nt) gv[rg][nt] = gr[nt * 16];
    }

    float mcontrib[20];
#pragma unroll
    for (int nt = 0; nt < 20; ++nt) mcontrib[nt] = 0.f;

#pragma unroll
    for (int rg = 0; rg < 4; ++rg) {
        const int row = mi * 16 + kq * 4 + rg;
        float lg[20];
#pragma unroll
        for (int nt = 0; nt < 20; ++nt)
            lg[nt] = (float)sm.L[row * LSTRIDE + nt * 16 + c];
        // per-lane argmax of noisy logits (lowest-index tie)
        float best = -1e30f; int bidx = 0;
#pragma unroll
        for (int nt = 0; nt < 20; ++nt) {
            const float nz = lg[nt] + gv[rg][nt];
            const int v = nt * 16 + c;
            if (nz > best) { best = nz; bidx = v; }
        }
        // 16-lane all-reduce argmax (xor 1..8 stays within quarter-wave)
#pragma unroll
        for (int mask = 1; mask <= 8; mask <<= 1) {
            const float ob = __shfl_xor(best, mask);
            const int   oi = __shfl_xor(bidx, mask);
            if (ob > best || (ob == best && oi < bidx)) { best = ob; bidx = oi; }
        }
        // noise-free softmax (no max-sub: logits O(+-6), f32-exact enough)
        float s = 0.f;
#pragma unroll
        for (int nt = 0; nt < 20; ++nt) { lg[nt] = __expf(lg[nt]); s += lg[nt]; }
#pragma unroll
        for (int mask = 1; mask <= 8; mask <<= 1) s += __shfl_xor(s, mask);
        const float inv = 1.f / s;
#pragma unroll
        for (int nt = 0; nt < 20; ++nt) mcontrib[nt] += lg[nt] * inv;
        // codevector gather + straight-through output (one-hot row bidx)
        const int ntok = bm * 64 + row;
        const float4* cvp = (const float4*)(cv + ((size_t)g * V_CODES + bidx) * CV_DIM)
                            + c * 2;
        const float4 v0 = cvp[0], v1 = cvp[1];
        float4* op = (float4*)(out + (size_t)ntok * 256 + g * CV_DIM) + c * 2;
        op[0] = v0; op[1] = v1;
    }

    // marginal: reduce 4 quarter-wave groups (same cols), LDS + global atomics
#pragma unroll
    for (int nt = 0; nt < 20; ++nt) {
        mcontrib[nt] += __shfl_xor(mcontrib[nt], 16);
        mcontrib[nt] += __shfl_xor(mcontrib[nt], 32);
    }
    if (lane < 16) {
#pragma unroll
        for (int nt = 0; nt < 20; ++nt)
            atomicAdd(&smarg[nt * 16 + c], mcontrib[nt]);
    }
    __syncthreads();
    for (int i = t; i < 320; i += 256)
        atomicAdd(marginal + g * V_CODES + i, smarg[i]);
}

// ---------------------------------------------------------------------------
// Kernel 2: finalize perplexity from the global marginal (640 floats).
// ---------------------------------------------------------------------------
__global__ __launch_bounds__(640)
void finalize(const float* __restrict__ marginal, float* __restrict__ perp_out) {
    __shared__ float terms[640];
    __shared__ float gsum[2];
    const int t = threadIdx.x;

    const float m = marginal[t] * (1.0f / (float)M_ROWS);
    terms[t] = -m * __logf(m + 1e-7f);
    __syncthreads();

    if (t < 128) {
        const int g = t >> 6, lane = t & 63;
        float e = 0.f;
#pragma unroll
        for (int j = 0; j < 5; ++j) e += terms[g * V_CODES + lane + 64 * j];
#pragma unroll
        for (int off = 32; off; off >>= 1) e += __shfl_down(e, off);
        if (lane == 0) gsum[g] = e;
    }
    __syncthreads();
    if (t == 0) perp_out[0] = __expf(gsum[0]) + __expf(gsum[1]);
}

// ---------------------------------------------------------------------------
extern "C" void kernel_launch(void* const* d_in, const int* in_sizes, int n_in,
                              void* d_out, int out_size, void* d_ws, size_t ws_size,
                              hipStream_t stream) {
    (void)in_sizes; (void)n_in; (void)out_size; (void)ws_size;
    const float* hs = (const float*)d_in[0];   // (8,2048,512) f32
    const float* W  = (const float*)d_in[1];   // (512,640)    f32
    const float* bi = (const float*)d_in[2];   // (640,)       f32
    const float* cv = (const float*)d_in[3];   // (1,640,128)  f32
    const float* gu = (const float*)d_in[4];   // (32768,320)  f32
    float* out = (float*)d_out;                // 16384*256 + 1

    // ws: Wt f16 (640 KB) + marginal (640 f32)
    _Float16* Wt       = (_Float16*)d_ws;
    float*    marginal = (float*)(Wt + (size_t)N_COLS * K_DIM);

    prepW<<<321, 256, 0, stream>>>(W, Wt, marginal);
    fused<<<dim3(256, 2), 256, 0, stream>>>(hs, Wt, bi, gu, cv, out, marginal);
    finalize<<<1, 640, 0, stream>>>(marginal, out + (size_t)M_ROWS * 256);
}